// Round 1
// baseline (174.527 us; speedup 1.0000x reference)
//
#include <hip/hip_runtime.h>

// DWT Haar 2x2 block transform:
//   in : (32, 3, 512, 512) fp32
//   out: (32, 12, 256, 256) fp32, sub-band order per (b,c): LL, LH, HL, HH
//
// v2: fully-coalesced reads. One thread = one 16B input chunk (4 cols) of a
// row-pair: lane-linear dwordx4 loads from both rows (vs v1's 32B-stride
// pattern that doubled L1 line-requests on the read path). Each thread
// computes 2 output cols for all 4 sub-bands; adjacent lane pairs then swap
// 8B halves via __shfl_xor(.,1) (quad-perm DPP) so even lanes hold full 16B
// LL/HL vectors and odd lanes LH/HH. Every global load AND store is a fully
// coalesced dwordx4 (16B/lane, dense 64B lines) — same VMEM instruction
// count per byte as v1, half the read line-requests.
// Stores remain REGULAR (not nontemporal): unchanged variable from v1.

typedef float v4f __attribute__((ext_vector_type(4)));

#define B_   32
#define C_   3
#define H_   512
#define W_   512
#define HO_  (H_/2)            // 256
#define WO_  (W_/2)            // 256
#define CHUNKS_ (W_/4)         // 128 input 16B-chunks per row
#define PLANE_ (HO_*WO_)       // 65536 floats per sub-band plane
#define NTHREADS_TOTAL (B_*C_*HO_*CHUNKS_)   // 3,145,728

__global__ __launch_bounds__(256) void dwt_haar_kernel(
        const float* __restrict__ x, float* __restrict__ out) {
    int g = blockIdx.x * blockDim.x + threadIdx.x;
    // decompose: g = ((bc*256 + h)*128 + chunk)
    int chunk = g & (CHUNKS_ - 1);          // 16B chunk in input row, 0..127
    int t     = g >> 7;
    int h     = t & (HO_ - 1);              // output row, 0..255
    int bc    = t >> 8;                     // b*3 + c, 0..95

    // Lane-linear loads: lane's chunk index is contiguous within the wave.
    const v4f* r0 = reinterpret_cast<const v4f*>(
        x + ((size_t)bc * H_ + 2 * (size_t)h) * W_) + chunk;
    v4f a0 = r0[0];            // row 2h,   cols 4*chunk .. 4*chunk+3
    v4f a1 = r0[W_ / 4];       // row 2h+1, same cols

    // Haar on the two col-pairs this lane owns (out cols 2*chunk, 2*chunk+1)
    float s0 = a0.x + a0.y, d0 = a0.x - a0.y;
    float s1 = a1.x + a1.y, d1 = a1.x - a1.y;
    float ll0 = (s0 + s1) * 0.5f, lh0 = (s0 - s1) * 0.5f;
    float hl0 = (d0 + d1) * 0.5f, hh0 = (d0 - d1) * 0.5f;

    float s2 = a0.z + a0.w, d2 = a0.z - a0.w;
    float s3 = a1.z + a1.w, d3 = a1.z - a1.w;
    float ll1 = (s2 + s3) * 0.5f, lh1 = (s2 - s3) * 0.5f;
    float hl1 = (d2 + d3) * 0.5f, hh1 = (d2 - d3) * 0.5f;

    // Pair exchange: even lane assembles LL & HL 16B vectors, odd lane LH & HH.
    int par = chunk & 1;
    // swap 1: even gives its LH pair, odd gives its LL pair
    float g1a = par ? ll0 : lh0;
    float g1b = par ? ll1 : lh1;
    float r1a = __shfl_xor(g1a, 1);
    float r1b = __shfl_xor(g1b, 1);
    // swap 2: even gives its HH pair, odd gives its HL pair
    float g2a = par ? hl0 : hh0;
    float g2b = par ? hl1 : hh1;
    float r2a = __shfl_xor(g2a, 1);
    float r2b = __shfl_xor(g2b, 1);

    v4f o1, o2;
    if (par == 0) {
        o1.x = ll0; o1.y = ll1; o1.z = r1a; o1.w = r1b;   // LL cols 4j..4j+3
        o2.x = hl0; o2.y = hl1; o2.z = r2a; o2.w = r2b;   // HL cols 4j..4j+3
    } else {
        o1.x = r1a; o1.y = r1b; o1.z = lh0; o1.w = lh1;   // LH cols 4j..4j+3
        o2.x = r2a; o2.y = r2b; o2.z = hh0; o2.w = hh1;   // HH cols 4j..4j+3
    }

    int b = bc / C_;
    int c = bc - b * C_;
    int j = chunk >> 1;        // 16B block in output row, 0..63
    // store 1 -> plane c*4 + par (LL or LH); store 2 -> plane c*4 + 2 + par
    v4f* o = reinterpret_cast<v4f*>(
        out + (((size_t)b * (C_ * 4) + c * 4 + par) * HO_ + h) * WO_
            + 4 * (size_t)j);
    o[0]                = o1;
    o[2 * (PLANE_ / 4)] = o2;   // +2 planes
}

extern "C" void kernel_launch(void* const* d_in, const int* in_sizes, int n_in,
                              void* d_out, int out_size, void* d_ws, size_t ws_size,
                              hipStream_t stream) {
    const float* x = (const float*)d_in[0];
    float* out = (float*)d_out;
    dim3 block(256);
    dim3 grid(NTHREADS_TOTAL / 256);   // 12288 blocks
    dwt_haar_kernel<<<grid, block, 0, stream>>>(x, out);
}

// Round 2
// 167.192 us; speedup vs baseline: 1.0439x; 1.0439x over previous
//
#include <hip/hip_runtime.h>

// DWT Haar 2x2 block transform:
//   in : (32, 3, 512, 512) fp32
//   out: (32, 12, 256, 256) fp32, sub-band order per (b,c): LL, LH, HL, HH
//
// v3: v1's exact thread mapping + arithmetic (absmax=0.0), ONE change:
// nontemporal (streaming) policy on EVERY global load and store.
// Rationale: v1 vs v2 showed perf is invariant to VMEM instruction shape
// (strided vs linear reads, 4 vs 2 stores: 58.8 vs 60.3 us) -> limiter is
// below L1. Kernel runs right after a 384 MiB poison fill that fills L3;
// regular loads/stores then allocate every line in L2+MALL (pure churn:
// zero intra-kernel reuse on either stream) and counters show all writes
// drain to HBM in-window anyway. nt bypasses allocation on both streams,
// making the kernel a pure HBM stream like the 6.3 TB/s copy benchmark.

typedef float v4f __attribute__((ext_vector_type(4)));  // native Clang vector

#define B_   32
#define C_   3
#define H_   512
#define W_   512
#define HO_  (H_/2)          // 256
#define WQ_  (W_/8)          // 64 col-quads per output row
#define PLANE_ (HO_*(W_/2))  // 65536 floats per sub-band plane
#define NTHREADS_TOTAL (B_*C_*HO_*WQ_)   // 1,572,864

__global__ __launch_bounds__(256) void dwt_haar_kernel(
        const float* __restrict__ x, float* __restrict__ out) {
    int g = blockIdx.x * blockDim.x + threadIdx.x;
    // decompose: g = ((bc*256 + h)*64 + wq)
    int wq = g & (WQ_ - 1);
    int t  = g >> 6;
    int h  = t & (HO_ - 1);
    int bc = t >> 8;               // b*3 + c, 0..95

    // input: 2 rows x 2 v4f loads (32B per row), 16B aligned, streaming
    const v4f* row0 = reinterpret_cast<const v4f*>(
        x + ((size_t)bc * H_ + 2 * (size_t)h) * W_) + 2 * wq;
    const v4f* row1 = row0 + (W_ / 4);   // next row, +512 floats
    v4f r0a = __builtin_nontemporal_load(row0);
    v4f r0b = __builtin_nontemporal_load(row0 + 1);
    v4f r1a = __builtin_nontemporal_load(row1);
    v4f r1b = __builtin_nontemporal_load(row1 + 1);

    v4f LL, LH, HL, HH;
    {   float a = r0a.x, b = r0a.y, c = r1a.x, d = r1a.y;
        LL.x = (a + b + c + d) * 0.5f;  LH.x = (a + b - c - d) * 0.5f;
        HL.x = (a - b + c - d) * 0.5f;  HH.x = (a - b - c + d) * 0.5f; }
    {   float a = r0a.z, b = r0a.w, c = r1a.z, d = r1a.w;
        LL.y = (a + b + c + d) * 0.5f;  LH.y = (a + b - c - d) * 0.5f;
        HL.y = (a - b + c - d) * 0.5f;  HH.y = (a - b - c + d) * 0.5f; }
    {   float a = r0b.x, b = r0b.y, c = r1b.x, d = r1b.y;
        LL.z = (a + b + c + d) * 0.5f;  LH.z = (a + b - c - d) * 0.5f;
        HL.z = (a - b + c - d) * 0.5f;  HH.z = (a - b - c + d) * 0.5f; }
    {   float a = r0b.z, b = r0b.w, c = r1b.z, d = r1b.w;
        LL.w = (a + b + c + d) * 0.5f;  LH.w = (a + b - c - d) * 0.5f;
        HL.w = (a - b + c - d) * 0.5f;  HH.w = (a - b - c + d) * 0.5f; }

    int b = bc / C_;
    int c = bc - b * C_;
    // out[b][c*4+s][h][w], planes contiguous at PLANE_ stride
    v4f* obase = reinterpret_cast<v4f*>(
        out + (((size_t)b * (C_ * 4) + c * 4) * HO_ + h) * (W_ / 2)
            + 4 * (size_t)wq);
    __builtin_nontemporal_store(LL, obase);
    __builtin_nontemporal_store(LH, obase + PLANE_ / 4);
    __builtin_nontemporal_store(HL, obase + 2 * (PLANE_ / 4));
    __builtin_nontemporal_store(HH, obase + 3 * (PLANE_ / 4));
}

extern "C" void kernel_launch(void* const* d_in, const int* in_sizes, int n_in,
                              void* d_out, int out_size, void* d_ws, size_t ws_size,
                              hipStream_t stream) {
    const float* x = (const float*)d_in[0];
    float* out = (float*)d_out;
    dim3 block(256);
    dim3 grid(NTHREADS_TOTAL / 256);   // 6144 blocks
    dwt_haar_kernel<<<grid, block, 0, stream>>>(x, out);
}